// Round 15
// baseline (516.401 us; speedup 1.0000x reference)
//
#include <hip/hip_runtime.h>
#include <stdint.h>

#define B_ 512
#define D_ 1024
#define M_ 32768

typedef _Float16 half8 __attribute__((ext_vector_type(8)));
typedef _Float16 half4 __attribute__((ext_vector_type(4)));
typedef float f32x4 __attribute__((ext_vector_type(4)));

// ---------- sortable key helpers (monotonic float <-> u32) ----------
__device__ __forceinline__ unsigned f2k(float f) {
    unsigned b = __float_as_uint(f);
    return (b & 0x80000000u) ? ~b : (b | 0x80000000u);
}
__device__ __forceinline__ float k2f(unsigned k) {
    unsigned b = (k & 0x80000000u) ? (k & 0x7FFFFFFFu) : ~k;
    return __uint_as_float(b);
}
// monotonic double -> u64 key
__device__ __forceinline__ unsigned long long d2k(double d) {
    unsigned long long b = (unsigned long long)__double_as_longlong(d);
    return (b & 0x8000000000000000ull) ? ~b : (b | 0x8000000000000000ull);
}

// ---------- fused encoder GEMM + W_dec transpose (grid role-split) ----------
// Round-15: split_x fused away. A (x - ib)*2048 -> fp16 conversion happens in
// GEMM staging (reg-stage from x/ib, swizzled ds_write, same formula as the
// old split_x -> A values bit-identical). One less kernel launch; x (2MB) is
// L2/L3-resident so re-reads are free. (256,3): R13 proved (256,5) spills.
__global__ __launch_bounds__(256, 3) void enc_tr(
    const float* __restrict__ x, const float* __restrict__ ib,
    const float* __restrict__ wenc, const float* __restrict__ nb,
    _Float16* __restrict__ preact,
    const float* __restrict__ wdec, _Float16* __restrict__ wdt)
{
    __shared__ alignas(16) char smem[32768];   // GEMM: lA 16KB + lB 16KB; epi 32KB; tr 16.6KB

    const int tid = threadIdx.x;
    const int chunk = blockIdx.x >> 8;

    if (chunk % 3 != 0) {
        // ---------------- transpose role: 4 tiles of 64x64, fp16 out ----------------
        const int sub = (chunk - 1 - chunk / 3) * 256 + (blockIdx.x & 255);  // [0,2048)
        float* tile = (float*)smem;               // [64][65] floats
        const int r = tid >> 2;                   // [0,64)
        const int q4 = (tid & 3) * 16;            // 16-wide quarter
        for (int s = 0; s < 4; ++s) {
            int tix = sub * 4 + s;                // [0,8192)
            int x0 = (tix & 511) * 64;            // M coord
            int y0 = (tix >> 9) * 64;             // D coord
            const float* src = wdec + (size_t)(y0 + r) * M_ + x0 + q4;
            float4 v0 = *(const float4*)(src + 0);
            float4 v1 = *(const float4*)(src + 4);
            float4 v2 = *(const float4*)(src + 8);
            float4 v3 = *(const float4*)(src + 12);
            float* dst = &tile[r * 65 + q4];
            dst[0] = v0.x;  dst[1] = v0.y;  dst[2] = v0.z;  dst[3] = v0.w;
            dst[4] = v1.x;  dst[5] = v1.y;  dst[6] = v1.z;  dst[7] = v1.w;
            dst[8] = v2.x;  dst[9] = v2.y;  dst[10] = v2.z; dst[11] = v2.w;
            dst[12] = v3.x; dst[13] = v3.y; dst[14] = v3.z; dst[15] = v3.w;
            __syncthreads();
            half8 h0, h1;
#pragma unroll
            for (int i = 0; i < 8; ++i) h0[i] = (_Float16)tile[(q4 + i) * 65 + r];
#pragma unroll
            for (int i = 0; i < 8; ++i) h1[i] = (_Float16)tile[(q4 + 8 + i) * 65 + r];
            _Float16* od = wdt + (size_t)(x0 + r) * D_ + y0 + q4;
            *(half8*)(od + 0) = h0;
            *(half8*)(od + 8) = h1;
            __syncthreads();
        }
        return;
    }

    // ---------------- GEMM role: 128x128 tile ----------------
    _Float16* lA0 = (_Float16*)smem;            // [2][128*32] halfs (16KB)
    _Float16* lB0 = (_Float16*)(smem + 16384);  // [2][128*32] halfs (16KB)

    const int sub = (chunk / 3) * 256 + (blockIdx.x & 255);   // [0,1024)
    const int lane = tid & 63;
    const int wv = tid >> 6;
    const int wvr = wv >> 1;          // 0..1 -> M half (64 rows)
    const int wvc = wv & 1;           // 0..1 -> N half (64 cols)

    const int lb = sub >> 3;                      // [0,128)
    const int j0 = ((sub & 7) * 32 + (lb >> 2)) * 128;
    const int i0 = (lb & 3) * 128;

    const int ln15 = lane & 15;
    const int kq = (lane >> 4) * 8;   // half index of 16B chunk within 64B row

    f32x4 acc1[4][4];
#pragma unroll
    for (int r = 0; r < 4; ++r)
#pragma unroll
        for (int c = 0; c < 4; ++c)
            acc1[r][c] = (f32x4){0.f, 0.f, 0.f, 0.f};

    // reg-staging map (A and B identical): row = tid>>1, float offset (tid&1)*16
    const int rW = tid >> 1;                 // [0,128)
    const int c16 = (tid & 1) * 16;          // float/half index within 32-wide k
    const int sw = ((rW >> 1) & 3) << 3;     // swizzle for 8-half groups
    const int g0 = c16 ^ sw;                 // swizzled group starts
    const int g1 = (c16 + 8) ^ sw;

    const int rowA = wvr * 64 + ln15;
    const int rowB = wvc * 64 + ln15;

#define LOADAB(k0)                                                                         \
    do {                                                                                   \
        const float* xp = x + (size_t)(i0 + rW) * 1024 + (k0) + c16;                       \
        xv0 = *(const float4*)xp;                                                          \
        xv1 = *(const float4*)(xp + 4);                                                    \
        xv2 = *(const float4*)(xp + 8);                                                    \
        xv3 = *(const float4*)(xp + 12);                                                   \
        const float* wp = wenc + (size_t)(j0 + rW) * 1024 + (k0) + c16;                    \
        wv0 = *(const float4*)wp;                                                          \
        wv1 = *(const float4*)(wp + 4);                                                    \
        wv2 = *(const float4*)(wp + 8);                                                    \
        wv3 = *(const float4*)(wp + 12);                                                   \
    } while (0)

#define LOADIB(k0)                                                                         \
    do {                                                                                   \
        const float* ip = ib + (k0) + c16;                                                 \
        iv0 = *(const float4*)ip;                                                          \
        iv1 = *(const float4*)(ip + 4);                                                    \
        iv2 = *(const float4*)(ip + 8);                                                    \
        iv3 = *(const float4*)(ip + 12);                                                   \
    } while (0)

#define WRITEAB(s)                                                                         \
    do {                                                                                   \
        half8 a0, a1, b0, b1;                                                              \
        a0[0] = (_Float16)((xv0.x - iv0.x) * 2048.0f); a0[1] = (_Float16)((xv0.y - iv0.y) * 2048.0f); \
        a0[2] = (_Float16)((xv0.z - iv0.z) * 2048.0f); a0[3] = (_Float16)((xv0.w - iv0.w) * 2048.0f); \
        a0[4] = (_Float16)((xv1.x - iv1.x) * 2048.0f); a0[5] = (_Float16)((xv1.y - iv1.y) * 2048.0f); \
        a0[6] = (_Float16)((xv1.z - iv1.z) * 2048.0f); a0[7] = (_Float16)((xv1.w - iv1.w) * 2048.0f); \
        a1[0] = (_Float16)((xv2.x - iv2.x) * 2048.0f); a1[1] = (_Float16)((xv2.y - iv2.y) * 2048.0f); \
        a1[2] = (_Float16)((xv2.z - iv2.z) * 2048.0f); a1[3] = (_Float16)((xv2.w - iv2.w) * 2048.0f); \
        a1[4] = (_Float16)((xv3.x - iv3.x) * 2048.0f); a1[5] = (_Float16)((xv3.y - iv3.y) * 2048.0f); \
        a1[6] = (_Float16)((xv3.z - iv3.z) * 2048.0f); a1[7] = (_Float16)((xv3.w - iv3.w) * 2048.0f); \
        *(half8*)&lA0[(s) * 4096 + rW * 32 + g0] = a0;                                     \
        *(half8*)&lA0[(s) * 4096 + rW * 32 + g1] = a1;                                     \
        b0[0] = (_Float16)(wv0.x * 2048.0f); b0[1] = (_Float16)(wv0.y * 2048.0f);          \
        b0[2] = (_Float16)(wv0.z * 2048.0f); b0[3] = (_Float16)(wv0.w * 2048.0f);          \
        b0[4] = (_Float16)(wv1.x * 2048.0f); b0[5] = (_Float16)(wv1.y * 2048.0f);          \
        b0[6] = (_Float16)(wv1.z * 2048.0f); b0[7] = (_Float16)(wv1.w * 2048.0f);          \
        b1[0] = (_Float16)(wv2.x * 2048.0f); b1[1] = (_Float16)(wv2.y * 2048.0f);          \
        b1[2] = (_Float16)(wv2.z * 2048.0f); b1[3] = (_Float16)(wv2.w * 2048.0f);          \
        b1[4] = (_Float16)(wv3.x * 2048.0f); b1[5] = (_Float16)(wv3.y * 2048.0f);          \
        b1[6] = (_Float16)(wv3.z * 2048.0f); b1[7] = (_Float16)(wv3.w * 2048.0f);          \
        *(half8*)&lB0[(s) * 4096 + rW * 32 + g0] = b0;                                     \
        *(half8*)&lB0[(s) * 4096 + rW * 32 + g1] = b1;                                     \
    } while (0)

    float4 xv0, xv1, xv2, xv3, wv0, wv1, wv2, wv3, iv0, iv1, iv2, iv3;
    // ---- prologue: tiles 0,1 ----
    LOADAB(0);
    LOADIB(0);
    asm volatile("s_waitcnt vmcnt(0)" ::: "memory");
    WRITEAB(0);
    LOADAB(32);
    LOADIB(32);
    asm volatile("s_waitcnt vmcnt(0)" ::: "memory");
    WRITEAB(1);
    asm volatile("s_waitcnt lgkmcnt(0)" ::: "memory");
    __builtin_amdgcn_s_barrier();

    int cur = 0;
    for (int k0 = 0; k0 < 1024; k0 += 32) {
        if (k0 + 64 < 1024) LOADAB(k0 + 64);   // A/B(k+2) reg-loads fly under MFMA

        half8 aH[4], bH[4];
#pragma unroll
        for (int r = 0; r < 4; ++r) {
            const int ra = rowA + r * 16;
            const int ka = kq ^ (((ra >> 1) & 3) << 3);
            aH[r] = *(const half8*)&lA0[cur * 4096 + ra * 32 + ka];
        }
#pragma unroll
        for (int c = 0; c < 4; ++c) {
            const int rb = rowB + c * 16;
            const int kb = kq ^ (((rb >> 1) & 3) << 3);
            bH[c] = *(const half8*)&lB0[cur * 4096 + rb * 32 + kb];
        }
#pragma unroll
        for (int r = 0; r < 4; ++r)
#pragma unroll
            for (int c = 0; c < 4; ++c)
                acc1[r][c] = __builtin_amdgcn_mfma_f32_16x16x32_f16(aH[r], bH[c], acc1[r][c], 0, 0, 0);

        if (k0 + 32 < 1024) {
            asm volatile("s_waitcnt lgkmcnt(0)" ::: "memory");
            __builtin_amdgcn_s_barrier();

            if (k0 + 64 < 1024) {
                LOADIB(k0 + 64);                                   // ib slice (L1/L2-hot)
                asm volatile("s_waitcnt vmcnt(0)" ::: "memory");   // drain A/B(k+2) + ib
                WRITEAB(cur);                                      // convert + swizzled ds_write
            }
            asm volatile("s_waitcnt lgkmcnt(0)" ::: "memory");
            __builtin_amdgcn_s_barrier();
        }
        cur ^= 1;
    }
#undef LOADAB
#undef LOADIB
#undef WRITEAB

    // ---- epilogue: repack C-tile via LDS, 16B-per-thread coalesced stores ----
    asm volatile("s_waitcnt lgkmcnt(0)" ::: "memory");
    __builtin_amdgcn_s_barrier();                    // all waves done with lA/lB
    _Float16* ct = (_Float16*)smem;                  // [128][128] halfs, 32KB
    const float s1 = 0x1p-22f;
#pragma unroll
    for (int c = 0; c < 4; ++c) {
        int n = wvc * 64 + c * 16 + ln15;            // tile-local col
        float nbv = nb[j0 + n];
#pragma unroll
        for (int r = 0; r < 4; ++r) {
            int mb = wvr * 64 + r * 16 + (lane >> 4) * 4;   // tile-local row
#pragma unroll
            for (int e = 0; e < 4; ++e)
                ct[(mb + e) * 128 + n] = (_Float16)(acc1[r][c][e] * s1 + nbv);
        }
    }
    __syncthreads();
#pragma unroll
    for (int s = 0; s < 8; ++s) {
        int idx = s * 256 + tid;                     // [0,2048) 16B chunks
        int row = idx >> 4;                          // [0,128)
        int off8 = (idx & 15) * 8;                   // half offset within 128
        *(half8*)(preact + (size_t)(i0 + row) * M_ + j0 + off8) = *(half8*)&ct[row * 128 + off8];
    }
}

// ---------- fused select + f64-exact resolve + sparse decode (one block/row) ----------
// Round-15: decode loops merged -- exact top-32 is always within sidx[0..48),
// so one 128-loop with wave-uniform membership flags computes mul AND
// rec/m0/m1 (kills 32 redundant wdt row-gathers per block).
__global__ __launch_bounds__(1024, 2) void selresdec(
    const _Float16* __restrict__ preact, const int* __restrict__ steps,
    const float* __restrict__ x, const float* __restrict__ ib,
    const float* __restrict__ wenc, const float* __restrict__ nb,
    const _Float16* __restrict__ wdt,
    float* __restrict__ out_tidx, float* __restrict__ out_tval,
    float* __restrict__ out_aidx, float* __restrict__ out_aval,
    float* __restrict__ o_recon, float* __restrict__ o_multik,
    float* __restrict__ o_mat0, float* __restrict__ o_mat1)
{
    __shared__ unsigned histU[4096];
    __shared__ unsigned histM[4096];
    __shared__ unsigned coarseU[256];
    __shared__ unsigned coarseM[256];
    __shared__ unsigned long long candU[512];
    __shared__ unsigned long long candM[512];
    __shared__ double xcs[1024];
    __shared__ double part[128][8];
    __shared__ unsigned long long kU[64];
    __shared__ unsigned long long kM[128];
    __shared__ float vU[64];
    __shared__ float vM[128];
    __shared__ int sidx[128];
    __shared__ float sval[128];
    __shared__ int auxm[80];
    __shared__ unsigned tflag[48];
    __shared__ float trv[48];
    __shared__ unsigned cntU, cntM, thrU, thrM, cbU, cbM, cumU, cumM;

    const int t = threadIdx.x;
    const int b = blockIdx.x;
    const half8* rowh = (const half8*)(preact + (size_t)b * M_);

    for (int i = t; i < 4096; i += 1024) { histU[i] = 0; histM[i] = 0; }
    if (t < 512) { candU[t] = 0ULL; candM[t] = 0ULL; }
    if (t == 0) { cntU = 0; cntM = 0; }
    xcs[t] = (double)x[(size_t)b * 1024 + t] - (double)ib[t];
    if (t < 64)  { kU[t] = 0ULL; vU[t] = 0.f; }
    if (t < 128) { kM[t] = 0ULL; vM[t] = 0.f; }
    if (t < 48)  { tflag[t] = 0u; trv[t] = 0.f; }
    __syncthreads();

    // ---- dead mask: bit p*8+e for m = (t + p*1024)*8 + e ----
    unsigned deadmask = 0;
#pragma unroll
    for (int p = 0; p < 4; ++p) {
        int base = 2 * t + 2048 * p;              // int4 index
        int4 s0 = ((const int4*)steps)[base];
        int4 s1 = ((const int4*)steps)[base + 1];
        unsigned mb = 0;
        if (s0.x + 1 > 256) mb |= 1u;
        if (s0.y + 1 > 256) mb |= 2u;
        if (s0.z + 1 > 256) mb |= 4u;
        if (s0.w + 1 > 256) mb |= 8u;
        if (s1.x + 1 > 256) mb |= 16u;
        if (s1.y + 1 > 256) mb |= 32u;
        if (s1.z + 1 > 256) mb |= 64u;
        if (s1.w + 1 > 256) mb |= 128u;
        deadmask |= mb << (p * 8);
    }

    // ---- single memory pass: load fp16 row into registers + histogram ----
    half8 v[4];
#pragma unroll
    for (int p = 0; p < 4; ++p) {
        v[p] = rowh[t + p * 1024];
#pragma unroll
        for (int e = 0; e < 8; ++e) {
            float val = (float)v[p][e];
            if (val > 0.f) {                       // positives only (thresholds ~ +1.7)
                unsigned key = f2k(val) >> 20;
                atomicAdd(&histU[key], 1u);
                if ((deadmask >> (p * 8 + e)) & 1u) atomicAdd(&histM[key], 1u);
            }
        }
    }
    __syncthreads();

    // ---- coarse sums ----
    if (t < 256) {
        unsigned s = 0;
#pragma unroll
        for (int j = 0; j < 16; ++j) s += histU[t * 16 + j];
        coarseU[t] = s;
    } else if (t < 512) {
        int c = t - 256;
        unsigned s = 0;
#pragma unroll
        for (int j = 0; j < 16; ++j) s += histM[c * 16 + j];
        coarseM[c] = s;
    }
    __syncthreads();

    // ---- joint Hillis-Steele suffix scan ----
    for (int off = 1; off < 256; off <<= 1) {
        unsigned xv = 0;
        if (t < 256)      xv = coarseU[t] + (t + off < 256 ? coarseU[t + off] : 0u);
        else if (t < 512) { int c = t - 256; xv = coarseM[c] + (c + off < 256 ? coarseM[c + off] : 0u); }
        __syncthreads();
        if (t < 256)      coarseU[t] = xv;
        else if (t < 512) coarseM[t - 256] = xv;
        __syncthreads();
    }

    // ---- crossing bins ----
    if (t < 256) {
        unsigned S = coarseU[t];
        unsigned Sn = (t < 255) ? coarseU[t + 1] : 0u;
        if (S >= 128u && (t == 255 || Sn < 128u)) { cbU = (unsigned)t; cumU = Sn; }
    } else if (t < 512) {
        int c = t - 256;
        unsigned S = coarseM[c];
        unsigned Sn = (c < 255) ? coarseM[c + 1] : 0u;
        if (S >= 64u && (c == 255 || Sn < 64u)) { cbM = (unsigned)c; cumM = Sn; }
        if (c == 0 && S < 64u) { cbM = 0u; cumM = Sn; }
    }
    __syncthreads();

    // ---- fine scans ----
    if (t == 0) {
        unsigned cum = cumU;
        int base = (int)cbU * 16, tb = base;
        for (int f = base + 15; f >= base; --f) {
            unsigned h = histU[f];
            if (cum + h >= 128u) { tb = f; break; }
            cum += h;
        }
        thrU = (unsigned)tb;
    }
    if (t == 64) {
        unsigned cum = cumM;
        int base = (int)cbM * 16, tb = base;
        for (int f = base + 15; f >= base; --f) {
            unsigned h = histM[f];
            if (cum + h >= 64u) { tb = f; break; }
            cum += h;
        }
        thrM = (unsigned)(tb > 0 ? tb - 1 : 0);
    }
    __syncthreads();

    const unsigned TU = thrU, TM = thrM;

    // ---- candidate collection straight from registers ----
#pragma unroll
    for (int p = 0; p < 4; ++p) {
#pragma unroll
        for (int e = 0; e < 8; ++e) {
            float val = (float)v[p][e];
            unsigned key = f2k(val);
            int m = (t + p * 1024) * 8 + e;
            if ((key >> 20) >= TU) {
                unsigned pz = atomicAdd(&cntU, 1u);
                if (pz < 512u) candU[pz] = ((unsigned long long)key << 32) | (unsigned)(~m);
            }
            if (((deadmask >> (p * 8 + e)) & 1u) && (key >> 20) >= TM) {
                unsigned pz = atomicAdd(&cntM, 1u);
                if (pz < 512u) candM[pz] = ((unsigned long long)key << 32) | (unsigned)(~m);
            }
        }
    }
    __syncthreads();

    // ---- bitonic sort: threads 0-511 -> candU, 512-1023 -> candM ----
    {
        unsigned long long* arr = (t < 512) ? candU : candM;
        const unsigned i = (unsigned)t & 511u;
        for (unsigned kk = 2; kk <= 512; kk <<= 1) {
            for (unsigned j = kk >> 1; j > 0; j >>= 1) {
                unsigned ixj = i ^ j;
                if (ixj > i) {
                    bool desc = ((i & kk) == 0);
                    unsigned long long a = arr[i], c = arr[ixj];
                    if (desc ? (a < c) : (a > c)) { arr[i] = c; arr[ixj] = a; }
                }
                unsigned nj = (j > 1) ? (j >> 1) : ((kk << 1) <= 512u ? kk : 0u);
                if (j >= 64 || nj >= 64) __syncthreads();
                else asm volatile("s_waitcnt lgkmcnt(0)" ::: "memory");
            }
        }
    }
    __syncthreads();

    // ---- sel/aux into LDS ----
    if (t < 128) {
        unsigned long long c = candU[t];
        unsigned m = ~(unsigned)c;
        float vv = k2f((unsigned)(c >> 32));
        sidx[t] = (int)m;
        sval[t] = vv > 0.f ? vv : 0.f;
    }
    if (t < 80) {
        unsigned long long c = candM[t];
        auxm[t] = c ? (int)(~(unsigned)c) : -1;
    }
    __syncthreads();

    // ---- f64 resolve: 8-way d-split over all 1024 threads, 128 candidates ----
    {
        const int ci = t >> 3, q = t & 7;
        int m = (ci < 48) ? sidx[ci] : auxm[ci - 48];
        if (m >= 0) {
            const float* w = wenc + (size_t)m * 1024 + q * 128;
            const double* xq = xcs + q * 128;
            double a0 = 0.0, a1 = 0.0, a2 = 0.0, a3 = 0.0;
            for (int d = 0; d < 128; d += 4) {
                float4 wv = *(const float4*)(w + d);
                a0 = fma((double)wv.x, xq[d + 0], a0);
                a1 = fma((double)wv.y, xq[d + 1], a1);
                a2 = fma((double)wv.z, xq[d + 2], a2);
                a3 = fma((double)wv.w, xq[d + 3], a3);
            }
            part[ci][q] = ((a0 + a1) + (a2 + a3));
        }
    }
    __syncthreads();

    // ---- combine partials, build keys ----
    if (t < 128) {
        int m = (t < 48) ? sidx[t] : auxm[t - 48];
        if (m >= 0) {
            double vd = (((part[t][0] + part[t][1]) + (part[t][2] + part[t][3]))
                       + ((part[t][4] + part[t][5]) + (part[t][6] + part[t][7])))
                      + (double)nb[m];
            unsigned long long key = (d2k(vd) & 0xFFFFFFFFFFFF0000ull)
                                   | (unsigned long long)((~(unsigned)m) & 0xFFFFu);
            float vf = (float)vd;
            if (t < 48) { kU[t] = key; vU[t] = vf; }
            else        { kM[t - 48] = key; vM[t - 48] = vf; }
        }
    }
    __syncthreads();

    // ---- sort kU (64) and kM (128) ----
    for (unsigned kk = 2; kk <= 128; kk <<= 1) {
        for (unsigned j = kk >> 1; j > 0; j >>= 1) {
            unsigned i = (unsigned)t, ixj = i ^ j;
            if (kk <= 64 && i < 64 && ixj > i) {
                bool desc = ((i & kk) == 0);
                unsigned long long a = kU[i], c = kU[ixj];
                if (desc ? (a < c) : (a > c)) {
                    kU[i] = c; kU[ixj] = a;
                    float fa = vU[i]; vU[i] = vU[ixj]; vU[ixj] = fa;
                }
            }
            if (i < 128 && ixj > i) {
                bool desc = ((i & kk) == 0);
                unsigned long long a = kM[i], c = kM[ixj];
                if (desc ? (a < c) : (a > c)) {
                    kM[i] = c; kM[ixj] = a;
                    float fa = vM[i]; vM[i] = vM[ixj]; vM[ixj] = fa;
                }
            }
            __syncthreads();
        }
    }

    if (t < 32) {
        unsigned mm = (~(unsigned)kU[t]) & 0xFFFFu;
        float vv = vU[t];
        float rv = vv > 0.f ? vv : 0.f;
        out_tidx[b * 32 + t] = (float)mm;
        out_tval[b * 32 + t] = rv;
        // membership flags: exact top-32 always within sidx[0..48)
        for (int j = 0; j < 48; ++j)
            if (sidx[j] == (int)mm) { tflag[j] = 1u; trv[j] = rv; }
    }
    if (t < 64) {
        unsigned mm = (~(unsigned)kM[t]) & 0xFFFFu;
        float vv = vM[t];
        out_aidx[b * 64 + t] = (float)mm;
        out_aval[b * 64 + t] = vv > 0.f ? vv : 0.f;
    }
    __syncthreads();

    // ---- sparse decode: single 128-loop; rec/m0/m1 via membership flags ----
    {
        const int d = t;
        float bias = ib[d];
        float mul = bias, rec = bias, m0 = bias, m1 = bias;
        for (int k = 0; k < 128; ++k) {
            float vv = sval[k];
            float w = (float)wdt[(size_t)sidx[k] * D_ + d];
            mul += vv * w;
            if (k < 48 && tflag[k]) {              // wave-uniform branch
                float rvv = trv[k];
                int idx = sidx[k];
                rec += rvv * w;
                if (idx < 16384) {
                    m1 += rvv * w;
                    if (idx < 4096) m0 += rvv * w;
                }
            }
        }
        size_t o = (size_t)b * D_ + d;
        o_recon[o]  = rec;
        o_multik[o] = mul;
        o_mat0[o]   = m0;
        o_mat1[o]   = m1;
    }
}

extern "C" void kernel_launch(void* const* d_in, const int* in_sizes, int n_in,
                              void* d_out, int out_size, void* d_ws, size_t ws_size,
                              hipStream_t stream)
{
    const float* x     = (const float*)d_in[0];
    const float* wenc  = (const float*)d_in[1];
    const float* wdec  = (const float*)d_in[2];
    const float* ib    = (const float*)d_in[3];
    const float* nb    = (const float*)d_in[4];
    const int*   steps = (const int*)d_in[5];
    float* out = (float*)d_out;

    char* ws = (char*)d_ws;
    _Float16*  preact  = (_Float16*)ws;                           // [0, 32MB)
    _Float16*  wdt     = (_Float16*)(ws + 67108864);              // [64MB, 128MB)

    float* out_recon  = out;
    float* out_multik = out + 524288;
    float* out_mat0   = out + 1048576;
    float* out_mat1   = out + 1572864;
    float* out_tidx   = out + 2097152;
    float* out_tval   = out + 2097152 + 16384;
    float* out_aidx   = out + 2097152 + 32768;
    float* out_aval   = out + 2097152 + 32768 + 32768;

    enc_tr<<<dim3(3072), dim3(256), 0, stream>>>(x, ib, wenc, nb, preact, wdec, wdt);
    selresdec<<<dim3(512), dim3(1024), 0, stream>>>(
        preact, steps, x, ib, wenc, nb, wdt,
        out_tidx, out_tval, out_aidx, out_aval,
        out_recon, out_multik, out_mat0, out_mat1);
}

// Round 16
// 451.793 us; speedup vs baseline: 1.1430x; 1.1430x over previous
//
#include <hip/hip_runtime.h>
#include <stdint.h>

#define B_ 512
#define D_ 1024
#define M_ 32768

typedef _Float16 half8 __attribute__((ext_vector_type(8)));
typedef _Float16 half4 __attribute__((ext_vector_type(4)));
typedef float f32x4 __attribute__((ext_vector_type(4)));

// ---------- sortable key helpers (monotonic float <-> u32) ----------
__device__ __forceinline__ unsigned f2k(float f) {
    unsigned b = __float_as_uint(f);
    return (b & 0x80000000u) ? ~b : (b | 0x80000000u);
}
__device__ __forceinline__ float k2f(unsigned k) {
    unsigned b = (k & 0x80000000u) ? (k & 0x7FFFFFFFu) : ~k;
    return __uint_as_float(b);
}
// monotonic double -> u64 key
__device__ __forceinline__ unsigned long long d2k(double d) {
    unsigned long long b = (unsigned long long)__double_as_longlong(d);
    return (b & 0x8000000000000000ull) ? ~b : (b | 0x8000000000000000ull);
}

// ---------- async global->LDS (16B per lane, wave-uniform base + lane*16) ----------
__device__ __forceinline__ void gld16(const void* g, void* l) {
    __builtin_amdgcn_global_load_lds(
        (__attribute__((address_space(1))) void*)(uintptr_t)g,
        (__attribute__((address_space(3))) void*)(unsigned)(uintptr_t)l,
        16, 0, 0);
}

// ---------- split x: xc = (x - ib) * 2048 -> fp16 hi ----------
__global__ __launch_bounds__(256) void split_x_k(
    const float* __restrict__ x, const float* __restrict__ ib,
    _Float16* __restrict__ xh)
{
    int i = blockIdx.x * 256 + threadIdx.x;   // float4 index, 131072 total
    float4 v = ((const float4*)x)[i];
    float4 bb = ((const float4*)ib)[i & 255];
    float a0 = (v.x - bb.x) * 2048.0f;
    float a1 = (v.y - bb.y) * 2048.0f;
    float a2 = (v.z - bb.z) * 2048.0f;
    float a3 = (v.w - bb.w) * 2048.0f;
    half4 hv = {(_Float16)a0, (_Float16)a1, (_Float16)a2, (_Float16)a3};
    ((half4*)xh)[i] = hv;
}

// ---------- fused encoder GEMM + W_dec transpose (grid role-split) ----------
// Round-16: FULL REVERT to the round-14 best (452.4 us). R15's split_x fusion
// replaced the async gld16 A-path (counted vmcnt(2), loads in flight across
// the barrier) with reg-staging + full vmcnt(0) drains -> the m233 stall came
// back (+32 us). Keep (256,3): R13 proved (256,5) spills the accumulators.
__global__ __launch_bounds__(256, 3) void enc_tr(
    const _Float16* __restrict__ xhf,
    const float* __restrict__ wenc, const float* __restrict__ nb,
    _Float16* __restrict__ preact,
    const float* __restrict__ wdec, _Float16* __restrict__ wdt)
{
    __shared__ alignas(16) char smem[32768];   // GEMM: lA 16KB + lB 16KB; epi 32KB; tr 16.6KB

    const int tid = threadIdx.x;
    const int chunk = blockIdx.x >> 8;

    if (chunk % 3 != 0) {
        // ---------------- transpose role: 4 tiles of 64x64, fp16 out ----------------
        const int sub = (chunk - 1 - chunk / 3) * 256 + (blockIdx.x & 255);  // [0,2048)
        float* tile = (float*)smem;               // [64][65] floats
        const int r = tid >> 2;                   // [0,64)
        const int q4 = (tid & 3) * 16;            // 16-wide quarter
        for (int s = 0; s < 4; ++s) {
            int tix = sub * 4 + s;                // [0,8192)
            int x0 = (tix & 511) * 64;            // M coord
            int y0 = (tix >> 9) * 64;             // D coord
            const float* src = wdec + (size_t)(y0 + r) * M_ + x0 + q4;
            float4 v0 = *(const float4*)(src + 0);
            float4 v1 = *(const float4*)(src + 4);
            float4 v2 = *(const float4*)(src + 8);
            float4 v3 = *(const float4*)(src + 12);
            float* dst = &tile[r * 65 + q4];
            dst[0] = v0.x;  dst[1] = v0.y;  dst[2] = v0.z;  dst[3] = v0.w;
            dst[4] = v1.x;  dst[5] = v1.y;  dst[6] = v1.z;  dst[7] = v1.w;
            dst[8] = v2.x;  dst[9] = v2.y;  dst[10] = v2.z; dst[11] = v2.w;
            dst[12] = v3.x; dst[13] = v3.y; dst[14] = v3.z; dst[15] = v3.w;
            __syncthreads();
            half8 h0, h1;
#pragma unroll
            for (int i = 0; i < 8; ++i) h0[i] = (_Float16)tile[(q4 + i) * 65 + r];
#pragma unroll
            for (int i = 0; i < 8; ++i) h1[i] = (_Float16)tile[(q4 + 8 + i) * 65 + r];
            _Float16* od = wdt + (size_t)(x0 + r) * D_ + y0 + q4;
            *(half8*)(od + 0) = h0;
            *(half8*)(od + 8) = h1;
            __syncthreads();
        }
        return;
    }

    // ---------------- GEMM role: 128x128 tile ----------------
    _Float16* lA0 = (_Float16*)smem;            // [2][128*32] halfs (16KB)
    _Float16* lB0 = (_Float16*)(smem + 16384);  // [2][128*32] halfs (16KB)

    const int sub = (chunk / 3) * 256 + (blockIdx.x & 255);   // [0,1024)
    const int lane = tid & 63;
    const int wv = tid >> 6;
    const int wvr = wv >> 1;          // 0..1 -> M half (64 rows)
    const int wvc = wv & 1;           // 0..1 -> N half (64 cols)

    const int lb = sub >> 3;                      // [0,128)
    const int j0 = ((sub & 7) * 32 + (lb >> 2)) * 128;
    const int i0 = (lb & 3) * 128;

    const int ln15 = lane & 15;
    const int kq = (lane >> 4) * 8;   // half index of 16B chunk within 64B row

    f32x4 acc1[4][4];
#pragma unroll
    for (int r = 0; r < 4; ++r)
#pragma unroll
        for (int c = 0; c < 4; ++c)
            acc1[r][c] = (f32x4){0.f, 0.f, 0.f, 0.f};

    const int o0 = tid * 16;                // [0,4096)
    const int o1 = o0 + 4096;               // [4096,8192)
    const int rA0 = o0 >> 6, rA1 = o1 >> 6; // [0,64), [64,128)
    const int cA0s = (o0 & 63) ^ (((rA0 >> 1) & 3) << 4);
    const int cA1s = (o1 & 63) ^ (((rA1 >> 1) & 3) << 4);

    const int rW = tid >> 1;                 // [0,128)
    const int c16 = (tid & 1) * 16;          // half/float index within 32-wide k
    const int sw = ((rW >> 1) & 3) << 3;     // swizzle for 8-half groups
    const int g0 = c16 ^ sw;                 // swizzled group starts
    const int g1 = (c16 + 8) ^ sw;

    const int rowA = wvr * 64 + ln15;
    const int rowB = wvc * 64 + ln15;

#define STAGEA(k0, s)                                                                      \
    do {                                                                                   \
        gld16((const char*)(xhf + (size_t)(i0 + rA0) * 1024 + (k0)) + cA0s, (char*)lA0 + (s) * 8192 + o0); \
        gld16((const char*)(xhf + (size_t)(i0 + rA1) * 1024 + (k0)) + cA1s, (char*)lA0 + (s) * 8192 + o1); \
    } while (0)

#define LOADB(k0)                                                                          \
    do {                                                                                   \
        const float* wp = wenc + (size_t)(j0 + rW) * 1024 + (k0) + c16;                    \
        wv0 = *(const float4*)wp;                                                          \
        wv1 = *(const float4*)(wp + 4);                                                    \
        wv2 = *(const float4*)(wp + 8);                                                    \
        wv3 = *(const float4*)(wp + 12);                                                   \
    } while (0)

#define WRITEB(s)                                                                          \
    do {                                                                                   \
        half8 b0, b1;                                                                      \
        b0[0] = (_Float16)(wv0.x * 2048.0f); b0[1] = (_Float16)(wv0.y * 2048.0f);          \
        b0[2] = (_Float16)(wv0.z * 2048.0f); b0[3] = (_Float16)(wv0.w * 2048.0f);          \
        b0[4] = (_Float16)(wv1.x * 2048.0f); b0[5] = (_Float16)(wv1.y * 2048.0f);          \
        b0[6] = (_Float16)(wv1.z * 2048.0f); b0[7] = (_Float16)(wv1.w * 2048.0f);          \
        b1[0] = (_Float16)(wv2.x * 2048.0f); b1[1] = (_Float16)(wv2.y * 2048.0f);          \
        b1[2] = (_Float16)(wv2.z * 2048.0f); b1[3] = (_Float16)(wv2.w * 2048.0f);          \
        b1[4] = (_Float16)(wv3.x * 2048.0f); b1[5] = (_Float16)(wv3.y * 2048.0f);          \
        b1[6] = (_Float16)(wv3.z * 2048.0f); b1[7] = (_Float16)(wv3.w * 2048.0f);          \
        *(half8*)&lB0[(s) * 4096 + rW * 32 + g0] = b0;                                     \
        *(half8*)&lB0[(s) * 4096 + rW * 32 + g1] = b1;                                     \
    } while (0)

    float4 wv0, wv1, wv2, wv3;
    // ---- prologue: tiles 0,1 ----
    LOADB(0);
    asm volatile("s_waitcnt vmcnt(0)" ::: "memory");
    WRITEB(0);
    STAGEA(0, 0);
    LOADB(32);
    STAGEA(32, 1);
    asm volatile("s_waitcnt vmcnt(2)" ::: "memory");   // drains A(0)+B(32) regs; A(32) flying
    WRITEB(1);
    asm volatile("s_waitcnt lgkmcnt(0)" ::: "memory");
    __builtin_amdgcn_s_barrier();

    int cur = 0;
    for (int k0 = 0; k0 < 1024; k0 += 32) {
        if (k0 + 64 < 1024) LOADB(k0 + 64);   // B(k+2) reg-loads fly under MFMA

        half8 aH[4], bH[4];
#pragma unroll
        for (int r = 0; r < 4; ++r) {
            const int ra = rowA + r * 16;
            const int ka = kq ^ (((ra >> 1) & 3) << 3);
            aH[r] = *(const half8*)&lA0[cur * 4096 + ra * 32 + ka];
        }
#pragma unroll
        for (int c = 0; c < 4; ++c) {
            const int rb = rowB + c * 16;
            const int kb = kq ^ (((rb >> 1) & 3) << 3);
            bH[c] = *(const half8*)&lB0[cur * 4096 + rb * 32 + kb];
        }
#pragma unroll
        for (int r = 0; r < 4; ++r)
#pragma unroll
            for (int c = 0; c < 4; ++c)
                acc1[r][c] = __builtin_amdgcn_mfma_f32_16x16x32_f16(aH[r], bH[c], acc1[r][c], 0, 0, 0);

        if (k0 + 32 < 1024) {
            asm volatile("s_waitcnt lgkmcnt(0)" ::: "memory");
            __builtin_amdgcn_s_barrier();

            if (k0 + 64 < 1024) {
                STAGEA(k0 + 64, cur);                              // +2 glds
                asm volatile("s_waitcnt vmcnt(2)" ::: "memory");   // drain A(k+1) glds + B(k+2) regs
                WRITEB(cur);
            } else {
                asm volatile("s_waitcnt vmcnt(0)" ::: "memory");
            }
            asm volatile("s_waitcnt lgkmcnt(0)" ::: "memory");
            __builtin_amdgcn_s_barrier();
        }
        cur ^= 1;
    }
#undef STAGEA
#undef LOADB
#undef WRITEB

    // ---- epilogue: repack C-tile via LDS, 16B-per-thread coalesced stores ----
    asm volatile("s_waitcnt lgkmcnt(0)" ::: "memory");
    __builtin_amdgcn_s_barrier();                    // all waves done with lA/lB
    _Float16* ct = (_Float16*)smem;                  // [128][128] halfs, 32KB
    const float s1 = 0x1p-22f;
#pragma unroll
    for (int c = 0; c < 4; ++c) {
        int n = wvc * 64 + c * 16 + ln15;            // tile-local col
        float nbv = nb[j0 + n];
#pragma unroll
        for (int r = 0; r < 4; ++r) {
            int mb = wvr * 64 + r * 16 + (lane >> 4) * 4;   // tile-local row
#pragma unroll
            for (int e = 0; e < 4; ++e)
                ct[(mb + e) * 128 + n] = (_Float16)(acc1[r][c][e] * s1 + nbv);
        }
    }
    __syncthreads();
#pragma unroll
    for (int s = 0; s < 8; ++s) {
        int idx = s * 256 + tid;                     // [0,2048) 16B chunks
        int row = idx >> 4;                          // [0,128)
        int off8 = (idx & 15) * 8;                   // half offset within 128
        *(half8*)(preact + (size_t)(i0 + row) * M_ + j0 + off8) = *(half8*)&ct[row * 128 + off8];
    }
}

// ---------- fused select + f64-exact resolve + sparse decode (one block/row) ----------
// Positive-only histograms; separate decode loops (R15's merged variant cost
// ~30 us via per-iteration flag reads; the 32 extra row-gathers are L2-hot).
__global__ __launch_bounds__(1024, 2) void selresdec(
    const _Float16* __restrict__ preact, const int* __restrict__ steps,
    const float* __restrict__ x, const float* __restrict__ ib,
    const float* __restrict__ wenc, const float* __restrict__ nb,
    const _Float16* __restrict__ wdt,
    float* __restrict__ out_tidx, float* __restrict__ out_tval,
    float* __restrict__ out_aidx, float* __restrict__ out_aval,
    float* __restrict__ o_recon, float* __restrict__ o_multik,
    float* __restrict__ o_mat0, float* __restrict__ o_mat1)
{
    __shared__ unsigned histU[4096];
    __shared__ unsigned histM[4096];
    __shared__ unsigned coarseU[256];
    __shared__ unsigned coarseM[256];
    __shared__ unsigned long long candU[512];
    __shared__ unsigned long long candM[512];
    __shared__ double xcs[1024];
    __shared__ double part[128][8];
    __shared__ unsigned long long kU[64];
    __shared__ unsigned long long kM[128];
    __shared__ float vU[64];
    __shared__ float vM[128];
    __shared__ int sidx[128];
    __shared__ float sval[128];
    __shared__ int auxm[80];
    __shared__ int ridx[32];
    __shared__ float rval[32];
    __shared__ unsigned cntU, cntM, thrU, thrM, cbU, cbM, cumU, cumM;

    const int t = threadIdx.x;
    const int b = blockIdx.x;
    const half8* rowh = (const half8*)(preact + (size_t)b * M_);

    for (int i = t; i < 4096; i += 1024) { histU[i] = 0; histM[i] = 0; }
    if (t < 512) { candU[t] = 0ULL; candM[t] = 0ULL; }
    if (t == 0) { cntU = 0; cntM = 0; }
    xcs[t] = (double)x[(size_t)b * 1024 + t] - (double)ib[t];
    if (t < 64)  { kU[t] = 0ULL; vU[t] = 0.f; }
    if (t < 128) { kM[t] = 0ULL; vM[t] = 0.f; }
    __syncthreads();

    // ---- dead mask: bit p*8+e for m = (t + p*1024)*8 + e ----
    unsigned deadmask = 0;
#pragma unroll
    for (int p = 0; p < 4; ++p) {
        int base = 2 * t + 2048 * p;              // int4 index
        int4 s0 = ((const int4*)steps)[base];
        int4 s1 = ((const int4*)steps)[base + 1];
        unsigned mb = 0;
        if (s0.x + 1 > 256) mb |= 1u;
        if (s0.y + 1 > 256) mb |= 2u;
        if (s0.z + 1 > 256) mb |= 4u;
        if (s0.w + 1 > 256) mb |= 8u;
        if (s1.x + 1 > 256) mb |= 16u;
        if (s1.y + 1 > 256) mb |= 32u;
        if (s1.z + 1 > 256) mb |= 64u;
        if (s1.w + 1 > 256) mb |= 128u;
        deadmask |= mb << (p * 8);
    }

    // ---- single memory pass: load fp16 row into registers + histogram ----
    half8 v[4];
#pragma unroll
    for (int p = 0; p < 4; ++p) {
        v[p] = rowh[t + p * 1024];
#pragma unroll
        for (int e = 0; e < 8; ++e) {
            float val = (float)v[p][e];
            if (val > 0.f) {                       // positives only (thresholds ~ +1.7)
                unsigned key = f2k(val) >> 20;
                atomicAdd(&histU[key], 1u);
                if ((deadmask >> (p * 8 + e)) & 1u) atomicAdd(&histM[key], 1u);
            }
        }
    }
    __syncthreads();

    // ---- coarse sums ----
    if (t < 256) {
        unsigned s = 0;
#pragma unroll
        for (int j = 0; j < 16; ++j) s += histU[t * 16 + j];
        coarseU[t] = s;
    } else if (t < 512) {
        int c = t - 256;
        unsigned s = 0;
#pragma unroll
        for (int j = 0; j < 16; ++j) s += histM[c * 16 + j];
        coarseM[c] = s;
    }
    __syncthreads();

    // ---- joint Hillis-Steele suffix scan ----
    for (int off = 1; off < 256; off <<= 1) {
        unsigned xv = 0;
        if (t < 256)      xv = coarseU[t] + (t + off < 256 ? coarseU[t + off] : 0u);
        else if (t < 512) { int c = t - 256; xv = coarseM[c] + (c + off < 256 ? coarseM[c + off] : 0u); }
        __syncthreads();
        if (t < 256)      coarseU[t] = xv;
        else if (t < 512) coarseM[t - 256] = xv;
        __syncthreads();
    }

    // ---- crossing bins ----
    if (t < 256) {
        unsigned S = coarseU[t];
        unsigned Sn = (t < 255) ? coarseU[t + 1] : 0u;
        if (S >= 128u && (t == 255 || Sn < 128u)) { cbU = (unsigned)t; cumU = Sn; }
    } else if (t < 512) {
        int c = t - 256;
        unsigned S = coarseM[c];
        unsigned Sn = (c < 255) ? coarseM[c + 1] : 0u;
        if (S >= 64u && (c == 255 || Sn < 64u)) { cbM = (unsigned)c; cumM = Sn; }
        if (c == 0 && S < 64u) { cbM = 0u; cumM = Sn; }
    }
    __syncthreads();

    // ---- fine scans ----
    if (t == 0) {
        unsigned cum = cumU;
        int base = (int)cbU * 16, tb = base;
        for (int f = base + 15; f >= base; --f) {
            unsigned h = histU[f];
            if (cum + h >= 128u) { tb = f; break; }
            cum += h;
        }
        thrU = (unsigned)tb;
    }
    if (t == 64) {
        unsigned cum = cumM;
        int base = (int)cbM * 16, tb = base;
        for (int f = base + 15; f >= base; --f) {
            unsigned h = histM[f];
            if (cum + h >= 64u) { tb = f; break; }
            cum += h;
        }
        thrM = (unsigned)(tb > 0 ? tb - 1 : 0);
    }
    __syncthreads();

    const unsigned TU = thrU, TM = thrM;

    // ---- candidate collection straight from registers ----
#pragma unroll
    for (int p = 0; p < 4; ++p) {
#pragma unroll
        for (int e = 0; e < 8; ++e) {
            float val = (float)v[p][e];
            unsigned key = f2k(val);
            int m = (t + p * 1024) * 8 + e;
            if ((key >> 20) >= TU) {
                unsigned pz = atomicAdd(&cntU, 1u);
                if (pz < 512u) candU[pz] = ((unsigned long long)key << 32) | (unsigned)(~m);
            }
            if (((deadmask >> (p * 8 + e)) & 1u) && (key >> 20) >= TM) {
                unsigned pz = atomicAdd(&cntM, 1u);
                if (pz < 512u) candM[pz] = ((unsigned long long)key << 32) | (unsigned)(~m);
            }
        }
    }
    __syncthreads();

    // ---- bitonic sort: threads 0-511 -> candU, 512-1023 -> candM ----
    {
        unsigned long long* arr = (t < 512) ? candU : candM;
        const unsigned i = (unsigned)t & 511u;
        for (unsigned kk = 2; kk <= 512; kk <<= 1) {
            for (unsigned j = kk >> 1; j > 0; j >>= 1) {
                unsigned ixj = i ^ j;
                if (ixj > i) {
                    bool desc = ((i & kk) == 0);
                    unsigned long long a = arr[i], c = arr[ixj];
                    if (desc ? (a < c) : (a > c)) { arr[i] = c; arr[ixj] = a; }
                }
                unsigned nj = (j > 1) ? (j >> 1) : ((kk << 1) <= 512u ? kk : 0u);
                if (j >= 64 || nj >= 64) __syncthreads();
                else asm volatile("s_waitcnt lgkmcnt(0)" ::: "memory");
            }
        }
    }
    __syncthreads();

    // ---- sel/aux into LDS ----
    if (t < 128) {
        unsigned long long c = candU[t];
        unsigned m = ~(unsigned)c;
        float vv = k2f((unsigned)(c >> 32));
        sidx[t] = (int)m;
        sval[t] = vv > 0.f ? vv : 0.f;
    }
    if (t < 80) {
        unsigned long long c = candM[t];
        auxm[t] = c ? (int)(~(unsigned)c) : -1;
    }
    __syncthreads();

    // ---- f64 resolve: 8-way d-split over all 1024 threads, 128 candidates ----
    {
        const int ci = t >> 3, q = t & 7;
        int m = (ci < 48) ? sidx[ci] : auxm[ci - 48];
        if (m >= 0) {
            const float* w = wenc + (size_t)m * 1024 + q * 128;
            const double* xq = xcs + q * 128;
            double a0 = 0.0, a1 = 0.0, a2 = 0.0, a3 = 0.0;
            for (int d = 0; d < 128; d += 4) {
                float4 wv = *(const float4*)(w + d);
                a0 = fma((double)wv.x, xq[d + 0], a0);
                a1 = fma((double)wv.y, xq[d + 1], a1);
                a2 = fma((double)wv.z, xq[d + 2], a2);
                a3 = fma((double)wv.w, xq[d + 3], a3);
            }
            part[ci][q] = ((a0 + a1) + (a2 + a3));
        }
    }
    __syncthreads();

    // ---- combine partials, build keys ----
    if (t < 128) {
        int m = (t < 48) ? sidx[t] : auxm[t - 48];
        if (m >= 0) {
            double vd = (((part[t][0] + part[t][1]) + (part[t][2] + part[t][3]))
                       + ((part[t][4] + part[t][5]) + (part[t][6] + part[t][7])))
                      + (double)nb[m];
            unsigned long long key = (d2k(vd) & 0xFFFFFFFFFFFF0000ull)
                                   | (unsigned long long)((~(unsigned)m) & 0xFFFFu);
            float vf = (float)vd;
            if (t < 48) { kU[t] = key; vU[t] = vf; }
            else        { kM[t - 48] = key; vM[t - 48] = vf; }
        }
    }
    __syncthreads();

    // ---- sort kU (64) and kM (128) ----
    for (unsigned kk = 2; kk <= 128; kk <<= 1) {
        for (unsigned j = kk >> 1; j > 0; j >>= 1) {
            unsigned i = (unsigned)t, ixj = i ^ j;
            if (kk <= 64 && i < 64 && ixj > i) {
                bool desc = ((i & kk) == 0);
                unsigned long long a = kU[i], c = kU[ixj];
                if (desc ? (a < c) : (a > c)) {
                    kU[i] = c; kU[ixj] = a;
                    float fa = vU[i]; vU[i] = vU[ixj]; vU[ixj] = fa;
                }
            }
            if (i < 128 && ixj > i) {
                bool desc = ((i & kk) == 0);
                unsigned long long a = kM[i], c = kM[ixj];
                if (desc ? (a < c) : (a > c)) {
                    kM[i] = c; kM[ixj] = a;
                    float fa = vM[i]; vM[i] = vM[ixj]; vM[ixj] = fa;
                }
            }
            __syncthreads();
        }
    }

    if (t < 32) {
        unsigned mm = (~(unsigned)kU[t]) & 0xFFFFu;
        float vv = vU[t];
        float rv = vv > 0.f ? vv : 0.f;
        ridx[t] = (int)mm;
        rval[t] = rv;
        out_tidx[b * 32 + t] = (float)mm;
        out_tval[b * 32 + t] = rv;
    }
    if (t < 64) {
        unsigned mm = (~(unsigned)kM[t]) & 0xFFFFu;
        float vv = vM[t];
        out_aidx[b * 64 + t] = (float)mm;
        out_aval[b * 64 + t] = vv > 0.f ? vv : 0.f;
    }
    __syncthreads();

    // ---- sparse decode: thread t owns output element d=t (k ascending) ----
    {
        const int d = t;
        float bias = ib[d];
        float mul = bias, rec = bias, m0 = bias, m1 = bias;
        for (int k = 0; k < 128; ++k) {
            float vv = sval[k];
            float w = (float)wdt[(size_t)sidx[k] * D_ + d];
            mul += vv * w;
        }
        for (int k = 0; k < 32; ++k) {
            int idx = ridx[k];
            float vv = rval[k];
            float w = (float)wdt[(size_t)idx * D_ + d];
            rec += vv * w;
            if (idx < 16384) {
                m1 += vv * w;
                if (idx < 4096) m0 += vv * w;
            }
        }
        size_t o = (size_t)b * D_ + d;
        o_recon[o]  = rec;
        o_multik[o] = mul;
        o_mat0[o]   = m0;
        o_mat1[o]   = m1;
    }
}

extern "C" void kernel_launch(void* const* d_in, const int* in_sizes, int n_in,
                              void* d_out, int out_size, void* d_ws, size_t ws_size,
                              hipStream_t stream)
{
    const float* x     = (const float*)d_in[0];
    const float* wenc  = (const float*)d_in[1];
    const float* wdec  = (const float*)d_in[2];
    const float* ib    = (const float*)d_in[3];
    const float* nb    = (const float*)d_in[4];
    const int*   steps = (const int*)d_in[5];
    float* out = (float*)d_out;

    char* ws = (char*)d_ws;
    _Float16*  preact  = (_Float16*)ws;                           // [0, 32MB)
    _Float16*  wdt     = (_Float16*)(ws + 67108864);              // [64MB, 128MB)
    _Float16*  xhf     = (_Float16*)(ws + 201326592);             // [192MB, +1MB)

    float* out_recon  = out;
    float* out_multik = out + 524288;
    float* out_mat0   = out + 1048576;
    float* out_mat1   = out + 1572864;
    float* out_tidx   = out + 2097152;
    float* out_tval   = out + 2097152 + 16384;
    float* out_aidx   = out + 2097152 + 32768;
    float* out_aval   = out + 2097152 + 32768 + 32768;

    split_x_k<<<dim3(512), dim3(256), 0, stream>>>(x, ib, xhf);
    enc_tr<<<dim3(3072), dim3(256), 0, stream>>>(xhf, wenc, nb, preact, wdec, wdt);
    selresdec<<<dim3(512), dim3(1024), 0, stream>>>(
        preact, steps, x, ib, wenc, nb, wdt,
        out_tidx, out_tval, out_aidx, out_aval,
        out_recon, out_multik, out_mat0, out_mat1);
}